// Round 4
// baseline (502.572 us; speedup 1.0000x reference)
//
#include <hip/hip_runtime.h>
#include <hip/hip_bf16.h>

#define B_  512
#define T_  200
#define NS  1000
#define M_  50
#define DK  64
#define DV  64
#define H_  128

typedef __hip_bfloat16 bf16;

// Flag-dispatched float load: isbf=0 -> fp32 array, isbf=1 -> bf16 array.
__device__ __forceinline__ float ldf(const void* p, int i, int isbf) {
    if (isbf) return __bfloat162float(((const bf16*)p)[i]);
    return ((const float*)p)[i];
}

// ---------------- sniff input dtype from mask (all-ones tensor) ----------------
__global__ void dk4_sniff(const void* __restrict__ mask, int* __restrict__ flag) {
    unsigned w = *(const unsigned*)mask;
    // fp32 1.0f -> 0x3F800000 ; two packed bf16 1.0s -> 0x3F803F80
    *flag = (w == 0x3F800000u) ? 0 : 1;
}

// ---------------- w_tab[s][m] = softmax_m(skill_embed[s] . key_memory[m]) ----------------
__global__ void dk4_wtab(const void* __restrict__ skill_embed,
                         const void* __restrict__ key_memory,
                         const int* __restrict__ flag,
                         float* __restrict__ w_tab) {
    int isbf = *flag;
    int s = blockIdx.x;          // 0..999
    int tid = threadIdx.x;       // 64 threads
    __shared__ float q[DK];
    __shared__ float lg[M_];
    __shared__ float inv_s;
    q[tid] = ldf(skill_embed, s * DK + tid, isbf);
    __syncthreads();
    if (tid < M_) {
        float acc = 0.f;
        for (int k = 0; k < DK; ++k)
            acc = fmaf(q[k], ldf(key_memory, tid * DK + k, isbf), acc);
        lg[tid] = acc;
    }
    __syncthreads();
    if (tid == 0) {
        float mx = -1e30f;
        for (int i = 0; i < M_; ++i) mx = fmaxf(mx, lg[i]);
        float sm = 0.f;
        for (int i = 0; i < M_; ++i) { float e = __expf(lg[i] - mx); lg[i] = e; sm += e; }
        inv_s = 1.f / sm;
    }
    __syncthreads();
    if (tid < M_) w_tab[s * M_ + tid] = lg[tid] * inv_s;
}

// ---------------- e_tab / a_tab over 2000 interaction rows ----------------
__global__ void dk4_eatab(const void* __restrict__ inter,
                          const void* __restrict__ eW, const void* __restrict__ eb,
                          const void* __restrict__ aW, const void* __restrict__ ab,
                          const int* __restrict__ flag,
                          float* __restrict__ e_tab, float* __restrict__ a_tab) {
    int isbf = *flag;
    int r = blockIdx.x;          // 0..1999
    int tid = threadIdx.x;       // 128 threads: 0..63 erase, 64..127 add
    __shared__ float vr[DV];
    if (tid < DV) vr[tid] = ldf(inter, r * DV + tid, isbf);
    __syncthreads();
    int v = tid & 63;
    bool isE = tid < 64;
    const void* W = isE ? eW : aW;
    float acc = ldf(isE ? eb : ab, v, isbf);
    for (int u = 0; u < DV; ++u)
        acc = fmaf(vr[u], ldf(W, u * DV + v, isbf), acc);
    if (isE) e_tab[r * DV + v] = 1.f / (1.f + __expf(-acc));
    else     a_tab[r * DV + v] = tanhf(acc);
}

// ---------------- hq_tab[s][j] = fc1_b[j] + sum_k q[k] * fc1_W[k][j] ----------------
__global__ void dk4_hqtab(const void* __restrict__ skill_embed,
                          const void* __restrict__ fc1W, const void* __restrict__ fc1b,
                          const int* __restrict__ flag,
                          float* __restrict__ hq_tab) {
    int isbf = *flag;
    int s = blockIdx.x;          // 0..999
    int tid = threadIdx.x;       // 128 threads
    __shared__ float q[DK];
    if (tid < DK) q[tid] = ldf(skill_embed, s * DK + tid, isbf);
    __syncthreads();
    float acc = ldf(fc1b, tid, isbf);
    for (int k = 0; k < DK; ++k)
        acc = fmaf(q[k], ldf(fc1W, k * H_ + tid, isbf), acc);
    hq_tab[s * H_ + tid] = acc;
}

// ---------------- sequential scan, one block per batch element ----------------
__global__ __launch_bounds__(256) void dk4_scan(
    const int*  __restrict__ skill_seq, const int* __restrict__ correct_seq,
    const void* __restrict__ mask,      const void* __restrict__ value_init,
    const void* __restrict__ fc1W,      const void* __restrict__ fc2W,
    const void* __restrict__ fc2b,
    const int*  __restrict__ flag,
    const float* __restrict__ w_tab, const float* __restrict__ e_tab,
    const float* __restrict__ a_tab, const float* __restrict__ hq_tab,
    float* __restrict__ out) {

    int isbf = *flag;
    int b   = blockIdx.x;        // 0..511
    int tid = threadIdx.x;       // 256
    int lane = tid & 63;
    int g    = tid >> 6;         // wave id 0..3

    __shared__ float mem[M_ * DV];     // 12.8 KB, row m owned by wave m%4
    __shared__ float W2lds[DV * H_];   // 32 KB: fc1_W rows 64..127 (reads half)
    __shared__ float wbuf[M_];
    __shared__ float red[4][DV];
    __shared__ float hpart[2][H_];
    __shared__ float fc2ws[H_];

    for (int i = tid; i < M_ * DV; i += 256) mem[i] = ldf(value_init, i, isbf);
    for (int i = tid; i < DV * H_;  i += 256) W2lds[i] = ldf(fc1W, DK * H_ + i, isbf);
    if (tid < H_) fc2ws[tid] = ldf(fc2W, tid, isbf);
    float fc2bias = ldf(fc2b, 0, isbf);
    float* out0 = out;                      // p * mask        (float32!)
    float* out1 = out + (size_t)B_ * T_;    // correct * mask  (float32!)
    __syncthreads();

    for (int t = 0; t < T_; ++t) {
        int s  = skill_seq[b * T_ + t];
        int c  = correct_seq[b * T_ + t];
        int ii = s + c * NS;

        if (tid < M_) wbuf[tid] = w_tab[s * M_ + tid];
        __syncthreads();                                   // (A)

        float ev = e_tab[ii * DV + lane];
        float av = a_tab[ii * DV + lane];
        float rdp = 0.f;
        for (int m = g; m < M_; m += 4) {
            float wm = wbuf[m];
            float mv = mem[m * DV + lane];
            rdp = fmaf(wm, mv, rdp);
            mem[m * DV + lane] = fmaf(mv, 1.f - wm * ev, wm * av);
        }
        red[g][lane] = rdp;
        __syncthreads();                                   // (B)

        if (g == 0)
            red[0][lane] = (red[0][lane] + red[1][lane]) + (red[2][lane] + red[3][lane]);
        __syncthreads();                                   // (C)

        {   // reads-half of fc1 from LDS: hpart[half][j] = sum over 32 v's
            int j = tid & 127;
            int half = tid >> 7;
            const float* Wp = &W2lds[(half * 32) * H_ + j];
            float acc = 0.f;
            #pragma unroll
            for (int v0 = 0; v0 < 32; ++v0)
                acc = fmaf(red[0][half * 32 + v0], Wp[v0 * H_], acc);
            hpart[half][j] = acc;
        }
        __syncthreads();                                   // (D)

        if (g == 0) {
            float h0 = hq_tab[s * H_ + lane]      + hpart[0][lane]      + hpart[1][lane];
            float h1 = hq_tab[s * H_ + 64 + lane] + hpart[0][64 + lane] + hpart[1][64 + lane];
            h0 = fmaxf(h0, 0.f);
            h1 = fmaxf(h1, 0.f);
            float x = fmaf(h0, fc2ws[lane], h1 * fc2ws[64 + lane]);
            for (int off = 32; off > 0; off >>= 1) x += __shfl_down(x, off, 64);
            if (lane == 0) {
                float mk = ldf(mask, b * T_ + t, isbf);
                float p  = 1.f / (1.f + __expf(-(x + fc2bias)));
                out0[b * T_ + t] = p * mk;
                out1[b * T_ + t] = (float)c * mk;
            }
        }
        __syncthreads();                                   // (E)
    }
}

extern "C" void kernel_launch(void* const* d_in, const int* in_sizes, int n_in,
                              void* d_out, int out_size, void* d_ws, size_t ws_size,
                              hipStream_t stream) {
    const int*  skill_seq   = (const int*)d_in[0];
    const int*  correct_seq = (const int*)d_in[1];
    const void* mask        = d_in[2];
    const void* skill_embed = d_in[3];
    const void* key_memory  = d_in[4];
    const void* value_init  = d_in[5];
    const void* inter       = d_in[6];
    const void* erase_W     = d_in[7];
    const void* erase_b     = d_in[8];
    const void* add_W       = d_in[9];
    const void* add_b       = d_in[10];
    const void* fc1_W       = d_in[11];
    const void* fc1_b       = d_in[12];
    const void* fc2_W       = d_in[13];
    const void* fc2_b       = d_in[14];
    float* out = (float*)d_out;

    int*   flag   = (int*)d_ws;
    float* ws     = (float*)d_ws + 16;        // tables start 64 B in
    float* w_tab  = ws;                       // 1000*50   =  50000 floats
    float* e_tab  = ws + 50000;               // 2000*64   = 128000
    float* a_tab  = ws + 178000;              // 2000*64   = 128000
    float* hq_tab = ws + 306000;              // 1000*128  = 128000  (total ~1.74 MB)

    dk4_sniff<<<1,      1,   0, stream>>>(mask, flag);
    dk4_wtab <<<NS,     64,  0, stream>>>(skill_embed, key_memory, flag, w_tab);
    dk4_eatab<<<2 * NS, 128, 0, stream>>>(inter, erase_W, erase_b, add_W, add_b, flag, e_tab, a_tab);
    dk4_hqtab<<<NS,     128, 0, stream>>>(skill_embed, fc1_W, fc1_b, flag, hq_tab);
    dk4_scan <<<B_,     256, 0, stream>>>(skill_seq, correct_seq, mask, value_init,
                                          fc1_W, fc2_W, fc2_b, flag,
                                          w_tab, e_tab, a_tab, hq_tab, out);
}

// Round 5
// 437.598 us; speedup vs baseline: 1.1485x; 1.1485x over previous
//
#include <hip/hip_runtime.h>
#include <hip/hip_bf16.h>

#define B_  512
#define T_  200
#define NS  1000
#define M_  50
#define MP  52          // mem rows padded to multiple of 4 (pad rows stay 0, w=0)
#define DK  64
#define DV  64
#define H_  128

typedef __hip_bfloat16 bf16;

// Flag-dispatched float load: isbf=0 -> fp32 array, isbf=1 -> bf16 array.
__device__ __forceinline__ float ldf(const void* p, int i, int isbf) {
    return isbf ? __bfloat162float(((const bf16*)p)[i]) : ((const float*)p)[i];
}
// mask is all-ones: fp32 1.0f -> 0x3F800000 ; two packed bf16 1.0s -> 0x3F803F80
__device__ __forceinline__ int sniff(const void* mask) {
    return (*(const unsigned*)mask == 0x3F800000u) ? 0 : 1;
}

// ---------------- fused precompute: w_tab | e/a_tab | hq_tab | out1 ----------------
__global__ __launch_bounds__(128) void dk5_tabs(
    const int* __restrict__ correct_seq, const void* __restrict__ mask,
    const void* __restrict__ skill_embed, const void* __restrict__ key_memory,
    const void* __restrict__ inter,
    const void* __restrict__ eW, const void* __restrict__ eb,
    const void* __restrict__ aW, const void* __restrict__ ab,
    const void* __restrict__ fc1W, const void* __restrict__ fc1b,
    float* __restrict__ w_tab, float* __restrict__ e_tab,
    float* __restrict__ a_tab, float* __restrict__ hq_tab,
    float* __restrict__ out1) {
    int isbf = sniff(mask);
    int blk = blockIdx.x, tid = threadIdx.x;
    if (blk < NS) {                           // ---- w_tab[s][m]
        int s = blk;
        __shared__ float q[DK]; __shared__ float lg[M_]; __shared__ float inv_s;
        if (tid < DK) q[tid] = ldf(skill_embed, s * DK + tid, isbf);
        __syncthreads();
        if (tid < M_) {
            float acc = 0.f;
            for (int k = 0; k < DK; ++k)
                acc = fmaf(q[k], ldf(key_memory, tid * DK + k, isbf), acc);
            lg[tid] = acc;
        }
        __syncthreads();
        if (tid == 0) {
            float mx = -1e30f;
            for (int i = 0; i < M_; ++i) mx = fmaxf(mx, lg[i]);
            float sm = 0.f;
            for (int i = 0; i < M_; ++i) { float e = __expf(lg[i] - mx); lg[i] = e; sm += e; }
            inv_s = 1.f / sm;
        }
        __syncthreads();
        if (tid < M_) w_tab[s * M_ + tid] = lg[tid] * inv_s;
    } else if (blk < 3 * NS) {                // ---- e_tab / a_tab
        int r = blk - NS;
        __shared__ float vr[DV];
        if (tid < DV) vr[tid] = ldf(inter, r * DV + tid, isbf);
        __syncthreads();
        int v = tid & 63; bool isE = tid < 64;
        const void* W = isE ? eW : aW;
        float acc = ldf(isE ? eb : ab, v, isbf);
        for (int u = 0; u < DV; ++u)
            acc = fmaf(vr[u], ldf(W, u * DV + v, isbf), acc);
        if (isE) e_tab[r * DV + v] = 1.f / (1.f + __expf(-acc));
        else     a_tab[r * DV + v] = tanhf(acc);
    } else if (blk < 4 * NS) {                // ---- hq_tab[s][j] (fc1 q-half + bias)
        int s = blk - 3 * NS;
        __shared__ float q2[DK];
        if (tid < DK) q2[tid] = ldf(skill_embed, s * DK + tid, isbf);
        __syncthreads();
        float acc = ldf(fc1b, tid, isbf);
        for (int k = 0; k < DK; ++k)
            acc = fmaf(q2[k], ldf(fc1W, k * H_ + tid, isbf), acc);
        hq_tab[s * H_ + tid] = acc;
    } else {                                  // ---- out1 = correct * mask (fully parallel)
        int i = (blk - 4 * NS) * 128 + tid;
        if (i < B_ * T_) out1[i] = (float)correct_seq[i] * ldf(mask, i, isbf);
    }
}

// ---------------- scan: ONE WAVE per sequence, zero cross-wave sync ----------------
// lane = 16*rg + cg owns mem rows m % 4 == rg, cols 4*cg .. 4*cg+3.
__global__ __launch_bounds__(64) void dk5_scan(
    const int*  __restrict__ skill_seq, const int* __restrict__ correct_seq,
    const void* __restrict__ mask,      const void* __restrict__ value_init,
    const void* __restrict__ fc1W,      const void* __restrict__ fc2W,
    const void* __restrict__ fc2b,
    const float* __restrict__ w_tab, const float* __restrict__ e_tab,
    const float* __restrict__ a_tab, const float* __restrict__ hq_tab,
    float* __restrict__ out0) {

    int isbf = sniff(mask);
    int b    = blockIdx.x;
    int lane = threadIdx.x;
    int cg   = lane & 15, rg = lane >> 4;
    int coff = 4 * cg;

    __shared__ float  memL[MP * DV];   // 13.3 KB
    __shared__ float4 redL[16];        // broadcast buffer for the read vector

    // init memory (+ zero pad rows so w=0 rows contribute 0, never NaN)
    for (int m = 0; m < M_; ++m) memL[m * DV + lane] = ldf(value_init, m * DV + lane, isbf);
    memL[M_ * DV + lane]      = 0.f;
    memL[M_ * DV + 64 + lane] = 0.f;

    // fc1 reads-half weights -> registers (column j = lane and j = lane+64)
    float w2a[DV], w2b[DV];
    #pragma unroll
    for (int v = 0; v < DV; ++v) {
        w2a[v] = ldf(fc1W, (DK + v) * H_ + lane,      isbf);
        w2b[v] = ldf(fc1W, (DK + v) * H_ + 64 + lane, isbf);
    }
    float f2a = ldf(fc2W, lane, isbf), f2b = ldf(fc2W, 64 + lane, isbf);
    float f2bias = ldf(fc2b, 0, isbf);

    const int base = b * T_;
    int s0 = skill_seq[base],     c0 = correct_seq[base];
    int s1 = skill_seq[base + 1], c1 = correct_seq[base + 1];

    // current-step (t=0) table values
    int ii0 = s0 + c0 * NS;
    float4 e4  = *(const float4*)&e_tab[ii0 * DV + coff];
    float4 a4  = *(const float4*)&a_tab[ii0 * DV + coff];
    float  wl  = (lane < M_) ? w_tab[s0 * M_ + lane] : 0.f;
    float  hq0 = hq_tab[s0 * H_ + lane];
    float  hq1 = hq_tab[s0 * H_ + 64 + lane];
    float  mk  = ldf(mask, base, isbf);
    __syncthreads();

    for (int t = 0; t < T_; ++t) {
        // ---- prefetch t+1 (s1/c1 already resident) and indices for t+2
        int tn  = (t + 1 < T_) ? t + 1 : T_ - 1;
        int t2  = (t + 2 < T_) ? t + 2 : T_ - 1;
        int ii1 = s1 + c1 * NS;
        float4 e4n  = *(const float4*)&e_tab[ii1 * DV + coff];
        float4 a4n  = *(const float4*)&a_tab[ii1 * DV + coff];
        float  wln  = (lane < M_) ? w_tab[s1 * M_ + lane] : 0.f;
        float  hq0n = hq_tab[s1 * H_ + lane];
        float  hq1n = hq_tab[s1 * H_ + 64 + lane];
        float  mkn  = ldf(mask, base + tn, isbf);
        int s2 = skill_seq[base + t2], c2 = correct_seq[base + t2];

        // ---- memory read + update (wave-private, no barriers)
        float4 rdp; rdp.x = rdp.y = rdp.z = rdp.w = 0.f;
        #pragma unroll
        for (int i = 0; i < MP / 4; ++i) {
            int m = 4 * i + rg;
            float wm = __shfl(wl, m, 64);
            float4 mv = *(float4*)&memL[m * DV + coff];
            rdp.x = fmaf(wm, mv.x, rdp.x);
            rdp.y = fmaf(wm, mv.y, rdp.y);
            rdp.z = fmaf(wm, mv.z, rdp.z);
            rdp.w = fmaf(wm, mv.w, rdp.w);
            float4 nv;
            nv.x = fmaf(wm, a4.x, fmaf(-(wm * e4.x), mv.x, mv.x));
            nv.y = fmaf(wm, a4.y, fmaf(-(wm * e4.y), mv.y, mv.y));
            nv.z = fmaf(wm, a4.z, fmaf(-(wm * e4.z), mv.z, mv.z));
            nv.w = fmaf(wm, a4.w, fmaf(-(wm * e4.w), mv.w, mv.w));
            *(float4*)&memL[m * DV + coff] = nv;
        }
        // reduce read across the 4 row-groups (lanes 16 apart share cols)
        rdp.x += __shfl_xor(rdp.x, 16, 64); rdp.x += __shfl_xor(rdp.x, 32, 64);
        rdp.y += __shfl_xor(rdp.y, 16, 64); rdp.y += __shfl_xor(rdp.y, 32, 64);
        rdp.z += __shfl_xor(rdp.z, 16, 64); rdp.z += __shfl_xor(rdp.z, 32, 64);
        rdp.w += __shfl_xor(rdp.w, 16, 64); rdp.w += __shfl_xor(rdp.w, 32, 64);
        if (lane < 16) redL[lane] = rdp;
        __syncthreads();   // single-wave barrier: cheap, orders redL write->read

        // ---- fc1 reads-half (weights in registers) + relu + fc2
        float h0 = hq0, h1 = hq1;
        #pragma unroll
        for (int vv = 0; vv < 16; ++vv) {
            float4 r4 = redL[vv];
            h0 = fmaf(r4.x, w2a[4 * vv + 0], h0); h1 = fmaf(r4.x, w2b[4 * vv + 0], h1);
            h0 = fmaf(r4.y, w2a[4 * vv + 1], h0); h1 = fmaf(r4.y, w2b[4 * vv + 1], h1);
            h0 = fmaf(r4.z, w2a[4 * vv + 2], h0); h1 = fmaf(r4.z, w2b[4 * vv + 2], h1);
            h0 = fmaf(r4.w, w2a[4 * vv + 3], h0); h1 = fmaf(r4.w, w2b[4 * vv + 3], h1);
        }
        h0 = fmaxf(h0, 0.f); h1 = fmaxf(h1, 0.f);
        float x = fmaf(h0, f2a, h1 * f2b);
        #pragma unroll
        for (int off = 1; off < 64; off <<= 1) x += __shfl_xor(x, off, 64);
        if (lane == 0) out0[base + t] = mk / (1.f + __expf(-(x + f2bias)));

        // ---- rotate prefetched state
        e4 = e4n; a4 = a4n; wl = wln; hq0 = hq0n; hq1 = hq1n; mk = mkn;
        s1 = s2; c1 = c2;
        __syncthreads();   // orders next iteration's redL overwrite after reads
    }
}

extern "C" void kernel_launch(void* const* d_in, const int* in_sizes, int n_in,
                              void* d_out, int out_size, void* d_ws, size_t ws_size,
                              hipStream_t stream) {
    const int*  skill_seq   = (const int*)d_in[0];
    const int*  correct_seq = (const int*)d_in[1];
    const void* mask        = d_in[2];
    const void* skill_embed = d_in[3];
    const void* key_memory  = d_in[4];
    const void* value_init  = d_in[5];
    const void* inter       = d_in[6];
    const void* erase_W     = d_in[7];
    const void* erase_b     = d_in[8];
    const void* add_W       = d_in[9];
    const void* add_b       = d_in[10];
    const void* fc1_W       = d_in[11];
    const void* fc1_b       = d_in[12];
    const void* fc2_W       = d_in[13];
    const void* fc2_b       = d_in[14];
    float* out = (float*)d_out;

    float* ws     = (float*)d_ws + 16;        // keep tables 64B-offset & 16B-aligned
    float* w_tab  = ws;                       // 1000*50   =  50000 floats
    float* e_tab  = ws + 50000;               // 2000*64   = 128000
    float* a_tab  = ws + 178000;              // 2000*64   = 128000
    float* hq_tab = ws + 306000;              // 1000*128  = 128000  (total ~1.74 MB)

    int tab_grid = 4 * NS + (B_ * T_ + 127) / 128;   // 4000 + 800
    dk5_tabs<<<tab_grid, 128, 0, stream>>>(correct_seq, mask, skill_embed, key_memory,
                                           inter, erase_W, erase_b, add_W, add_b,
                                           fc1_W, fc1_b,
                                           w_tab, e_tab, a_tab, hq_tab,
                                           out + (size_t)B_ * T_);
    dk5_scan<<<B_, 64, 0, stream>>>(skill_seq, correct_seq, mask, value_init,
                                    fc1_W, fc2_W, fc2_b,
                                    w_tab, e_tab, a_tab, hq_tab, out);
}

// Round 6
// 294.812 us; speedup vs baseline: 1.7047x; 1.4843x over previous
//
#include <hip/hip_runtime.h>
#include <hip/hip_bf16.h>

#define B_  512
#define T_  200
#define NS  1000
#define M_  50
#define DK  64
#define DV  64
#define H_  128

typedef __hip_bfloat16 bf16;

// Flag-dispatched float load: isbf=0 -> fp32 array, isbf=1 -> bf16 array.
__device__ __forceinline__ float ldf(const void* p, int i, int isbf) {
    return isbf ? __bfloat162float(((const bf16*)p)[i]) : ((const float*)p)[i];
}
// mask is all-ones: fp32 1.0f -> 0x3F800000 ; two packed bf16 1.0s -> 0x3F803F80
__device__ __forceinline__ int sniff(const void* mask) {
    return (*(const unsigned*)mask == 0x3F800000u) ? 0 : 1;
}

// ---------------- fused precompute: w_tab | e/a_tab | hq_tab | out1 ----------------
__global__ __launch_bounds__(128) void dk6_tabs(
    const int* __restrict__ correct_seq, const void* __restrict__ mask,
    const void* __restrict__ skill_embed, const void* __restrict__ key_memory,
    const void* __restrict__ inter,
    const void* __restrict__ eW, const void* __restrict__ eb,
    const void* __restrict__ aW, const void* __restrict__ ab,
    const void* __restrict__ fc1W, const void* __restrict__ fc1b,
    float* __restrict__ w_tab, float* __restrict__ e_tab,
    float* __restrict__ a_tab, float* __restrict__ hq_tab,
    float* __restrict__ out1) {
    int isbf = sniff(mask);
    int blk = blockIdx.x, tid = threadIdx.x;
    if (blk < NS) {                           // ---- w_tab[s][m], wave-parallel softmax
        int s = blk;
        __shared__ float q[DK];
        if (tid < DK) q[tid] = ldf(skill_embed, s * DK + tid, isbf);
        __syncthreads();
        if (tid < 64) {                       // wave 0 only
            float acc = 0.f;
            if (tid < M_) {
                for (int k = 0; k < DK; ++k)
                    acc = fmaf(q[k], ldf(key_memory, tid * DK + k, isbf), acc);
            }
            float val = (tid < M_) ? acc : -1e30f;
            float mx = val;
            #pragma unroll
            for (int off = 1; off < 64; off <<= 1) mx = fmaxf(mx, __shfl_xor(mx, off, 64));
            float ex = (tid < M_) ? __expf(val - mx) : 0.f;
            float sm = ex;
            #pragma unroll
            for (int off = 1; off < 64; off <<= 1) sm += __shfl_xor(sm, off, 64);
            if (tid < M_) w_tab[s * M_ + tid] = ex / sm;
        }
    } else if (blk < 3 * NS) {                // ---- e_tab / a_tab
        int r = blk - NS;
        __shared__ float vr[DV];
        if (tid < DV) vr[tid] = ldf(inter, r * DV + tid, isbf);
        __syncthreads();
        int v = tid & 63; bool isE = tid < 64;
        const void* W = isE ? eW : aW;
        float acc = ldf(isE ? eb : ab, v, isbf);
        for (int u = 0; u < DV; ++u)
            acc = fmaf(vr[u], ldf(W, u * DV + v, isbf), acc);
        if (isE) e_tab[r * DV + v] = 1.f / (1.f + __expf(-acc));
        else     a_tab[r * DV + v] = tanhf(acc);
    } else if (blk < 4 * NS) {                // ---- hq_tab[s][j] (fc1 q-half + bias)
        int s = blk - 3 * NS;
        __shared__ float q2[DK];
        if (tid < DK) q2[tid] = ldf(skill_embed, s * DK + tid, isbf);
        __syncthreads();
        float acc = ldf(fc1b, tid, isbf);
        for (int k = 0; k < DK; ++k)
            acc = fmaf(q2[k], ldf(fc1W, k * H_ + tid, isbf), acc);
        hq_tab[s * H_ + tid] = acc;
    } else {                                  // ---- out1 = correct * mask
        int i = (blk - 4 * NS) * 128 + tid;
        if (i < B_ * T_) out1[i] = (float)correct_seq[i] * ldf(mask, i, isbf);
    }
}

// ---------------- scan: 2 waves/block — wave0 = recurrence (mem in VGPRs),
// wave1 = fc1/fc2/output one step behind. One barrier per step. ----------------
__global__ __launch_bounds__(128) void dk6_scan(
    const int*  __restrict__ skill_seq, const int* __restrict__ correct_seq,
    const void* __restrict__ mask,      const void* __restrict__ value_init,
    const void* __restrict__ fc1W,      const void* __restrict__ fc2W,
    const void* __restrict__ fc2b,
    const float* __restrict__ w_tab, const float* __restrict__ e_tab,
    const float* __restrict__ a_tab, const float* __restrict__ hq_tab,
    float* __restrict__ out0) {

    int isbf = sniff(mask);
    int b    = blockIdx.x;
    int lane = threadIdx.x & 63;
    int g    = threadIdx.x >> 6;
    const int base = b * T_;

    __shared__ float4 pread4[2][16];   // double-buffered 64-float read vector

    if (g == 0) {
        // ================= producer: the serial recurrence =================
        // lane = column; mem[m] = value memory row m, this lane's column.
        float mem[M_];
        #pragma unroll
        for (int m = 0; m < M_; ++m) mem[m] = ldf(value_init, m * DV + lane, isbf);

        int s0 = skill_seq[base], c0 = correct_seq[base];
        int ii0 = s0 + c0 * NS;
        float e  = e_tab[ii0 * DV + lane];
        float a  = a_tab[ii0 * DV + lane];
        float wl = (lane < M_) ? w_tab[s0 * M_ + lane] : 0.f;
        int s1 = skill_seq[base + 1], c1 = correct_seq[base + 1];

        for (int t = 0; t < T_; ++t) {
            // prefetch step t+1 tables (s1/c1 resident), indices for t+2
            int t2  = (t + 2 < T_) ? t + 2 : T_ - 1;
            int ii1 = s1 + c1 * NS;
            float en  = e_tab[ii1 * DV + lane];
            float an  = a_tab[ii1 * DV + lane];
            float wln = (lane < M_) ? w_tab[s1 * M_ + lane] : 0.f;
            int s2 = skill_seq[base + t2], c2 = correct_seq[base + t2];

            // read + erase/add update, all in registers
            float acc = 0.f;
            #pragma unroll
            for (int m = 0; m < M_; ++m) {
                float wm = __shfl(wl, m, 64);
                float we = wm * e;
                acc = fmaf(wm, mem[m], acc);
                float u = fmaf(-we, mem[m], mem[m]);
                mem[m] = fmaf(wm, a, u);
            }
            ((float*)pread4[t & 1])[lane] = acc;

            e = en; a = an; wl = wln; s1 = s2; c1 = c2;
            __syncthreads();
        }
    } else {
        // ================= consumer: fc1(reads-half) + relu + fc2 + out =================
        float w2a[DV], w2b[DV];
        #pragma unroll
        for (int v = 0; v < DV; ++v) {
            w2a[v] = ldf(fc1W, (DK + v) * H_ + lane,      isbf);
            w2b[v] = ldf(fc1W, (DK + v) * H_ + 64 + lane, isbf);
        }
        float f2a = ldf(fc2W, lane, isbf), f2b = ldf(fc2W, 64 + lane, isbf);
        float f2bias = ldf(fc2b, 0, isbf);

        int s0 = skill_seq[base];
        float hqA0 = hq_tab[s0 * H_ + lane];
        float hqA1 = hq_tab[s0 * H_ + 64 + lane];
        float mkA  = ldf(mask, base, isbf);
        int sNext  = skill_seq[base + 1];
        float hqB0 = 0.f, hqB1 = 0.f, mkB = 0.f;

        for (int t = 0; t < T_; ++t) {
            if (t > 0) {
                // consume step t-1
                float h0 = hqB0, h1 = hqB1;
                const float4* rp = pread4[(t - 1) & 1];
                #pragma unroll
                for (int vv = 0; vv < 16; ++vv) {
                    float4 r4 = rp[vv];
                    h0 = fmaf(r4.x, w2a[4 * vv + 0], h0); h1 = fmaf(r4.x, w2b[4 * vv + 0], h1);
                    h0 = fmaf(r4.y, w2a[4 * vv + 1], h0); h1 = fmaf(r4.y, w2b[4 * vv + 1], h1);
                    h0 = fmaf(r4.z, w2a[4 * vv + 2], h0); h1 = fmaf(r4.z, w2b[4 * vv + 2], h1);
                    h0 = fmaf(r4.w, w2a[4 * vv + 3], h0); h1 = fmaf(r4.w, w2b[4 * vv + 3], h1);
                }
                h0 = fmaxf(h0, 0.f); h1 = fmaxf(h1, 0.f);
                float x = fmaf(h0, f2a, h1 * f2b);
                #pragma unroll
                for (int off = 1; off < 64; off <<= 1) x += __shfl_xor(x, off, 64);
                if (lane == 0) out0[base + t - 1] = mkB / (1.f + __expf(-(x + f2bias)));
            }
            // rotate: B <- values for step t (consumed next iteration)
            hqB0 = hqA0; hqB1 = hqA1; mkB = mkA;
            int tn = (t + 1 < T_) ? t + 1 : T_ - 1;
            int t2 = (t + 2 < T_) ? t + 2 : T_ - 1;
            hqA0 = hq_tab[sNext * H_ + lane];
            hqA1 = hq_tab[sNext * H_ + 64 + lane];
            mkA  = ldf(mask, base + tn, isbf);
            sNext = skill_seq[base + t2];
            __syncthreads();
        }
        {   // final step T-1
            float h0 = hqB0, h1 = hqB1;
            const float4* rp = pread4[(T_ - 1) & 1];
            #pragma unroll
            for (int vv = 0; vv < 16; ++vv) {
                float4 r4 = rp[vv];
                h0 = fmaf(r4.x, w2a[4 * vv + 0], h0); h1 = fmaf(r4.x, w2b[4 * vv + 0], h1);
                h0 = fmaf(r4.y, w2a[4 * vv + 1], h0); h1 = fmaf(r4.y, w2b[4 * vv + 1], h1);
                h0 = fmaf(r4.z, w2a[4 * vv + 2], h0); h1 = fmaf(r4.z, w2b[4 * vv + 2], h1);
                h0 = fmaf(r4.w, w2a[4 * vv + 3], h0); h1 = fmaf(r4.w, w2b[4 * vv + 3], h1);
            }
            h0 = fmaxf(h0, 0.f); h1 = fmaxf(h1, 0.f);
            float x = fmaf(h0, f2a, h1 * f2b);
            #pragma unroll
            for (int off = 1; off < 64; off <<= 1) x += __shfl_xor(x, off, 64);
            if (lane == 0) out0[base + T_ - 1] = mkB / (1.f + __expf(-(x + f2bias)));
        }
    }
}

extern "C" void kernel_launch(void* const* d_in, const int* in_sizes, int n_in,
                              void* d_out, int out_size, void* d_ws, size_t ws_size,
                              hipStream_t stream) {
    const int*  skill_seq   = (const int*)d_in[0];
    const int*  correct_seq = (const int*)d_in[1];
    const void* mask        = d_in[2];
    const void* skill_embed = d_in[3];
    const void* key_memory  = d_in[4];
    const void* value_init  = d_in[5];
    const void* inter       = d_in[6];
    const void* erase_W     = d_in[7];
    const void* erase_b     = d_in[8];
    const void* add_W       = d_in[9];
    const void* add_b       = d_in[10];
    const void* fc1_W       = d_in[11];
    const void* fc1_b       = d_in[12];
    const void* fc2_W       = d_in[13];
    const void* fc2_b       = d_in[14];
    float* out = (float*)d_out;

    float* ws     = (float*)d_ws + 16;
    float* w_tab  = ws;                       // 1000*50
    float* e_tab  = ws + 50000;               // 2000*64
    float* a_tab  = ws + 178000;              // 2000*64
    float* hq_tab = ws + 306000;              // 1000*128

    int tab_grid = 4 * NS + (B_ * T_ + 127) / 128;
    dk6_tabs<<<tab_grid, 128, 0, stream>>>(correct_seq, mask, skill_embed, key_memory,
                                           inter, erase_W, erase_b, add_W, add_b,
                                           fc1_W, fc1_b,
                                           w_tab, e_tab, a_tab, hq_tab,
                                           out + (size_t)B_ * T_);
    dk6_scan<<<B_, 128, 0, stream>>>(skill_seq, correct_seq, mask, value_init,
                                     fc1_W, fc2_W, fc2_b,
                                     w_tab, e_tab, a_tab, hq_tab, out);
}